// Round 3
// 439.564 us; speedup vs baseline: 1.0887x; 1.0887x over previous
//
#include <hip/hip_runtime.h>

#define DD 128

typedef __bf16 bf16x8 __attribute__((ext_vector_type(8)));
typedef float f32x4 __attribute__((ext_vector_type(4)));

static __device__ __forceinline__ unsigned short f2bf(float f) {
    unsigned int u = __float_as_uint(f);
    u += 0x7FFF + ((u >> 16) & 1);   // round-to-nearest-even
    return (unsigned short)(u >> 16);
}
static __device__ __forceinline__ float bf2f(unsigned short v) {
    return __uint_as_float(((unsigned)v) << 16);
}

// ---------------- CSR build ----------------

__global__ void k_zero(int* __restrict__ p, int n) {
    int i = blockIdx.x * 256 + threadIdx.x;
    if (i < n) p[i] = 0;
}

__global__ void k_count(const int* __restrict__ dst, int* __restrict__ cnt, int E) {
    int e = blockIdx.x * 256 + threadIdx.x;
    if (e < E) atomicAdd(&cnt[dst[e]], 1);
}

// scan phase 1: block-local inclusive scan into rp[i+1], block totals into bsum,
// dinv = rsqrt(deg+1).  49 blocks x 1024 — fully parallel (replaces 1-block serial scan).
__global__ __launch_bounds__(1024) void k_scan1(const int* __restrict__ cnt,
                                                int* __restrict__ rp,
                                                float* __restrict__ dinv,
                                                int* __restrict__ bsum, int N) {
    __shared__ int wsum[16];
    const int tid = threadIdx.x, lane = tid & 63, wid = tid >> 6;
    const int i = blockIdx.x * 1024 + tid;
    int v = (i < N) ? cnt[i] : 0;
    int s = v;
    for (int off = 1; off < 64; off <<= 1) {
        int t = __shfl_up(s, off, 64);
        if (lane >= off) s += t;
    }
    if (lane == 63) wsum[wid] = s;
    __syncthreads();
    int woff = 0, total = 0;
#pragma unroll
    for (int w2 = 0; w2 < 16; ++w2) {
        int t = wsum[w2];
        if (w2 < wid) woff += t;
        total += t;
    }
    if (i < N) {
        rp[i + 1] = woff + s;                 // block-local inclusive
        dinv[i] = rsqrtf((float)(v + 1));     // +1 self-loop
    }
    if (tid == 0) bsum[blockIdx.x] = total;
}

// scan phase 2: add exclusive prefix of block sums.
__global__ __launch_bounds__(1024) void k_scan2(const int* __restrict__ bsum,
                                                int* __restrict__ rp, int N) {
    __shared__ int boff_s;
    const int tid = threadIdx.x;
    if (tid < 64) {
        int v = (tid < (int)blockIdx.x) ? bsum[tid] : 0;   // nb <= 49 < 64
        for (int off = 32; off > 0; off >>= 1) v += __shfl_down(v, off, 64);
        if (tid == 0) boff_s = v;
    }
    __syncthreads();
    const int i = blockIdx.x * 1024 + tid;
    if (i < N) rp[i + 1] += boff_s;
    if (i == 0) rp[0] = 0;
}

// fill: consume cnt via atomicSub (no cursor array, no second zero pass); csr = src only (4B)
__global__ void k_fill(const int* __restrict__ ei, const int* __restrict__ rp,
                       int* __restrict__ cnt, int* __restrict__ csr, int E) {
    int e = blockIdx.x * 256 + threadIdx.x;
    if (e >= E) return;
    int s = ei[e], d = ei[E + e];
    int old = atomicSub(&cnt[d], 1);          // old in [1..deg]
    csr[rp[d] + old - 1] = s;
}

// ---------------- dense h = x @ W^T  (bf16 MFMA, fp32 accum, bf16 h out) ----
// h stored node-interleaved: h[n][m][128] -> each node's 4 matrix rows are 1 KB contiguous.

__global__ __launch_bounds__(256) void k_gemm(
    const float* __restrict__ x0, const float* __restrict__ x1,
    const float* __restrict__ x2, const float* __restrict__ x3,
    const float* __restrict__ W1, const float* __restrict__ W2,
    unsigned short* __restrict__ h, int N)
{
    const int m = blockIdx.y;
    const float* x = (m == 0) ? x0 : (m == 1) ? x1 : (m == 2) ? x2 : x3;
    const float* W = (m & 1) ? W2 : W1;   // m=0,2 -> W1 ; m=1,3 -> W2

    __shared__ unsigned short Ws[128 * 128];   // [c][k] bf16, 32 KB
    __shared__ unsigned short ts[64 * 136];    // stage stride 128; epilogue stride 136

    const int tid = threadIdx.x;
    const int n0 = blockIdx.x * 64;

    // stage W -> bf16 LDS
    for (int t = tid; t < 128 * 128 / 4; t += 256) {
        float4 v = ((const float4*)W)[t];
        ushort4 b;
        b.x = f2bf(v.x); b.y = f2bf(v.y); b.z = f2bf(v.z); b.w = f2bf(v.w);
        *(ushort4*)&Ws[t * 4] = b;
    }
    // stage x tile -> bf16 LDS (64 rows x 128 cols, stride 128)
    for (int t = tid; t < 64 * 32; t += 256) {
        int r = t >> 5;
        int n = n0 + r;
        float4 v = make_float4(0.f, 0.f, 0.f, 0.f);
        if (n < N) v = ((const float4*)(x + (size_t)n * DD))[t & 31];
        ushort4 b;
        b.x = f2bf(v.x); b.y = f2bf(v.y); b.z = f2bf(v.z); b.w = f2bf(v.w);
        *(ushort4*)&ts[r * 128 + (t & 31) * 4] = b;
    }
    __syncthreads();

    const int w    = tid >> 6;
    const int lane = tid & 63;
    const int am   = lane & 15;
    const int aq   = lane >> 4;
    const int r0   = w * 16;

    f32x4 acc[8] = {};
#pragma unroll
    for (int kk = 0; kk < 128; kk += 32) {
        bf16x8 af = *(const bf16x8*)&ts[(r0 + am) * 128 + kk + aq * 8];
#pragma unroll
        for (int ct = 0; ct < 8; ++ct) {
            bf16x8 bf = *(const bf16x8*)&Ws[(ct * 16 + am) * 128 + kk + aq * 8];
            acc[ct] = __builtin_amdgcn_mfma_f32_16x16x32_bf16(af, bf, acc[ct], 0, 0, 0);
        }
    }
    __syncthreads();   // all waves done reading ts before epilogue overwrite

    // C/D layout: col = lane&15, row = (lane>>4)*4 + reg  -> bf16 into ts (stride 136)
    const int cc = lane & 15;
    const int rr = (lane >> 4) * 4;
#pragma unroll
    for (int ct = 0; ct < 8; ++ct)
#pragma unroll
        for (int i = 0; i < 4; ++i)
            ts[(r0 + rr + i) * 136 + ct * 16 + cc] = f2bf(acc[ct][i]);
    __syncthreads();

    // coalesced store into interleaved layout: h[(n*4 + m)*128 + c]
#pragma unroll
    for (int k = 0; k < 4; ++k) {
        int f = k * 256 + tid;
        int row = f >> 4, ch = f & 15;
        int n = n0 + row;
        if (n < N) {
            uint4 v = *(const uint4*)&ts[row * 136 + ch * 8];
            *(uint4*)(h + ((size_t)n * 4 + m) * DD + ch * 8) = v;
        }
    }
}

// ---------------- aggregation: gather by dst via CSR (interleaved bf16 h) -----
// one block per node; 2 partitions x 128 threads; thread owns 4 cols of one matrix.
// Each edge reads ONE contiguous 1 KB row (all 4 matrices) -> long coalesced bursts.

__global__ __launch_bounds__(256) void k_gather(
    const int* __restrict__ rp, const int* __restrict__ csr,
    const float* __restrict__ dinv, const unsigned short* __restrict__ h,
    const float* __restrict__ b1, const float* __restrict__ b2,
    float* __restrict__ out, int N)
{
    const int n   = blockIdx.x;
    const int tid = threadIdx.x;
    const int p   = tid >> 7;            // edge partition 0/1
    const int idx = tid & 127;           // column slot over 4 matrices x 32 slots
    const int m   = idx >> 5;
    const int c   = (idx & 31) * 4;
    const size_t off = (size_t)idx * 4;  // ushort offset within the 512-wide node row

    const float dn = dinv[n];
    float ax = 0.f, ay = 0.f, az = 0.f, aw = 0.f;

    if (p == 0) {   // self-loop + bias
        const float sn = dn * dn;
        const float* bb = (m & 1) ? b2 : b1;
        ushort4 hv = *(const ushort4*)(h + (size_t)n * 512 + off);
        float4 bv = *(const float4*)(bb + c);
        ax = bf2f(hv.x) * sn + bv.x; ay = bf2f(hv.y) * sn + bv.y;
        az = bf2f(hv.z) * sn + bv.z; aw = bf2f(hv.w) * sn + bv.w;
    }

    const int j0 = rp[n], j1 = rp[n + 1];
    const int half = (j1 - j0 + 1) >> 1;
    int jb = j0 + p * half;
    const int je = p ? j1 : (j0 + half);

    for (; jb + 3 < je; jb += 4) {
        int s0 = csr[jb], s1 = csr[jb + 1], s2 = csr[jb + 2], s3 = csr[jb + 3];
        float w0 = dinv[s0] * dn, w1 = dinv[s1] * dn,
              w2 = dinv[s2] * dn, w3 = dinv[s3] * dn;
        ushort4 v0 = *(const ushort4*)(h + (size_t)s0 * 512 + off);
        ushort4 v1 = *(const ushort4*)(h + (size_t)s1 * 512 + off);
        ushort4 v2 = *(const ushort4*)(h + (size_t)s2 * 512 + off);
        ushort4 v3 = *(const ushort4*)(h + (size_t)s3 * 512 + off);
        ax += bf2f(v0.x) * w0 + bf2f(v1.x) * w1 + bf2f(v2.x) * w2 + bf2f(v3.x) * w3;
        ay += bf2f(v0.y) * w0 + bf2f(v1.y) * w1 + bf2f(v2.y) * w2 + bf2f(v3.y) * w3;
        az += bf2f(v0.z) * w0 + bf2f(v1.z) * w1 + bf2f(v2.z) * w2 + bf2f(v3.z) * w3;
        aw += bf2f(v0.w) * w0 + bf2f(v1.w) * w1 + bf2f(v2.w) * w2 + bf2f(v3.w) * w3;
    }
    for (; jb < je; ++jb) {
        int s0 = csr[jb];
        float wgt = dinv[s0] * dn;
        ushort4 v = *(const ushort4*)(h + (size_t)s0 * 512 + off);
        ax += bf2f(v.x) * wgt; ay += bf2f(v.y) * wgt;
        az += bf2f(v.z) * wgt; aw += bf2f(v.w) * wgt;
    }

    __shared__ float part[512];
    if (p == 1) *(float4*)&part[idx * 4] = make_float4(ax, ay, az, aw);
    __syncthreads();
    if (p == 0) {
        float4 t = *(const float4*)&part[idx * 4];
        f32x4 r;
        r.x = ax + t.x; r.y = ay + t.y; r.z = az + t.z; r.w = aw + t.w;
        // streaming store: out is never re-read -> keep L2 for h gathers
        __builtin_nontemporal_store(r, (f32x4*)(out + ((size_t)m * N + n) * DD + c));
    }
}

// ---------------- launch ----------------

extern "C" void kernel_launch(void* const* d_in, const int* in_sizes, int n_in,
                              void* d_out, int out_size, void* d_ws, size_t ws_size,
                              hipStream_t stream) {
    const float* x0 = (const float*)d_in[0];
    const float* x1 = (const float*)d_in[1];
    const float* x2 = (const float*)d_in[2];
    const float* x3 = (const float*)d_in[3];
    const int*   ei = (const int*)d_in[4];
    const float* W1 = (const float*)d_in[5];
    const float* b1 = (const float*)d_in[6];
    const float* W2 = (const float*)d_in[7];
    const float* b2 = (const float*)d_in[8];
    float* out = (float*)d_out;

    const int N = in_sizes[0] / DD;   // 50000
    const int E = in_sizes[4] / 2;    // 800000

    // workspace layout
    int*   cnt  = (int*)d_ws;                        // 65536
    int*   rp   = cnt + 65536;                       // 65536 (needs N+1)
    float* dinv = (float*)(rp + 65536);              // 65536
    int*   bsum = (int*)(dinv + 65536);              // 256
    int*   csr  = bsum + 256;                        // E ints (src only)
    unsigned short* h = (unsigned short*)(csr + E);  // interleaved [N][4][128] bf16 = 51.2 MB

    const int nb = (N + 1023) / 1024;                // 49

    k_zero <<<(N + 255) / 256, 256, 0, stream>>>(cnt, N);
    k_count<<<(E + 255) / 256, 256, 0, stream>>>(ei + E, cnt, E);
    k_scan1<<<nb, 1024, 0, stream>>>(cnt, rp, dinv, bsum, N);
    k_scan2<<<nb, 1024, 0, stream>>>(bsum, rp, N);
    k_fill <<<(E + 255) / 256, 256, 0, stream>>>(ei, rp, cnt, csr, E);

    dim3 g((N + 63) / 64, 4);
    k_gemm<<<g, 256, 0, stream>>>(x0, x1, x2, x3, W1, W2, h, N);

    k_gather<<<N, 256, 0, stream>>>(rp, csr, dinv, h, b1, b2, out, N);
}